// Round 9
// baseline (72.418 us; speedup 1.0000x reference)
//
#include <hip/hip_runtime.h>
#include <math.h>

// FreqEmbedding: seq [16,512,64] f32 -> out [16,512,65,64] f32
// reflect-pad(64) -> hanning(128) frames -> rfft(128) -> complex standardize
// over (L,F) per (B,C) -> abs.
//
// Pass 0 (pad): materialize reflect-padded input [16,640,64] (round-8, kept).
// Pass A (reduce): Parseval + symmetry identities (4 dot products) (proven).
// Pass B (write): PARITY-SPLIT lane-pair FFT. lam0=FFT32(E), lam1=FFT32(O);
//   one shfl exchange gives lam0 {E,O}[even], lam1 {E,O}[odd]; bin parity is
//   closed under the rfft unpack couplings (k <-> 32-k preserves parity), so
//   each lane computes ONLY its parity's Z and bins: no duplicated combine
//   work (round-6 flaw), flat ~64-f32 live state (round-4/8 flaw: 128-f32
//   state -> AGPR parking -> dep-latency-bound at 31% VALUBusy).

#define B_ 16
#define L_ 512
#define C_ 64
#define W_ 128
#define F_ 65
#define LP 640  // padded length
#define NLF (L_ * F_)  // 33280

// ---------- compile-time trig tables (fold to VALU literals) ----------
constexpr double kPI = 3.14159265358979323846;

constexpr double csin_(double x) {
  while (x > kPI) x -= 2.0 * kPI;
  while (x < -kPI) x += 2.0 * kPI;
  double t = x, s = x, x2 = x * x;
  for (int i = 1; i <= 24; ++i) {
    t *= -x2 / ((2.0 * i) * (2.0 * i + 1.0));
    s += t;
  }
  return s;
}
constexpr double ccos_(double x) { return csin_(kPI / 2.0 - x); }

constexpr int bitrev5(int n) {
  int r = 0;
  for (int i = 0; i < 5; ++i) r |= ((n >> i) & 1) << (4 - i);
  return r;
}

struct Tables {
  float win[128];           // hanning w_n
  float walt[128];          // (-1)^n w_n
  float w2[128];            // w_n^2
  float wg[128];            // w_n * G_n
  float t32r[16], t32i[16]; // exp(-2*pi*i*r/32)
  float e64r[33], e64i[33]; // exp(-2*pi*i*k/64), k=0..32
  float c128r[33], c128i[33]; // exp(-2*pi*i*k/128), k=0..32
  constexpr Tables()
      : win(), walt(), w2(), wg(), t32r(), t32i(), e64r(), e64i(), c128r(), c128i() {
    for (int n = 0; n < 128; ++n) {
      const double wd = 0.5 - 0.5 * ccos_(2.0 * kPI * n / 127.0);
      win[n] = (float)wd;
      walt[n] = (n & 1) ? (float)(-wd) : (float)wd;
      w2[n] = (float)(wd * wd);
      if (n == 0) {
        wg[n] = 0.0f;
      } else {
        const double G = csin_(kPI * n / 2.0) * csin_(65.0 * kPI * n / 128.0) /
                         csin_(kPI * n / 128.0);
        wg[n] = (float)(wd * G);
      }
    }
    for (int r = 0; r < 16; ++r) {
      t32r[r] = (float)ccos_(2.0 * kPI * r / 32.0);
      t32i[r] = (float)(-csin_(2.0 * kPI * r / 32.0));
    }
    for (int k = 0; k <= 32; ++k) {
      e64r[k] = (float)ccos_(2.0 * kPI * k / 64.0);
      e64i[k] = (float)(-csin_(2.0 * kPI * k / 64.0));
      c128r[k] = (float)ccos_(2.0 * kPI * k / 128.0);
      c128i[k] = (float)(-csin_(2.0 * kPI * k / 128.0));
    }
  }
};
constexpr Tables TBL{};

// branchless reflect into [0,512) for t in [-64, 575]
__device__ __forceinline__ int refl(int t) {
  const int a = max(t, -t);
  return min(a, 1022 - a);
}

__device__ __forceinline__ float fast_sqrt(float x) {
  float r;
  asm("v_sqrt_f32 %0, %1" : "=v"(r) : "v"(x));
  return r;
}

// ---------------- Pass 0: materialize reflect-padded input ----------------
__global__ void __launch_bounds__(256)
fe_pad_kernel(const float* __restrict__ seq, float* __restrict__ pad) {
  const int idx = blockIdx.x * 256 + threadIdx.x;  // b*LP*C + t*C + c
  const int c = idx & 63;
  const int row = idx >> 6;  // b*LP + t
  const int b = row / LP;
  const int t = row - b * LP;
  const int s = refl(t - 64);
  pad[idx] = seq[(b * L_ + s) * C_ + c];
}

// ws layout (floats): [0..1023] sum_re, [1024..2047] sum_im, [2048..3071] sum_sq,
//                     [4096 ..] padded input [16][640][64]
// ---------------- Pass A: Parseval reduce (on padded input) ----------------
__global__ void __launch_bounds__(256)
fe_reduce_kernel(const float* __restrict__ pad, float* __restrict__ acc) {
  const int p = blockIdx.x * 4 + (threadIdx.x >> 6);
  const int b = __builtin_amdgcn_readfirstlane(p >> 9);
  const int l = __builtin_amdgcn_readfirstlane(p & (L_ - 1));
  const int c = threadIdx.x & 63;

  const float* base = pad + ((size_t)(b * LP + l)) * C_ + c;

  float x0 = 0.f, x64 = 0.f, p2 = 0.f, d2 = 0.f;
#pragma unroll
  for (int n = 0; n < 128; ++n) {
    const float v = base[n * C_];
    x0 += TBL.win[n] * v;
    x64 += TBL.walt[n] * v;
    const float wv = TBL.w2[n] * v;
    p2 += wv * v;
    d2 += TBL.wg[n] * v;
  }

  const float sre = 0.5f * (x0 + x64);
  const float sim = -d2;
  const float ssq = 64.0f * p2 + 0.5f * (x0 * x0 + x64 * x64);

  __shared__ float red[3][256];
  const int tid = threadIdx.x;
  red[0][tid] = sre;
  red[1][tid] = sim;
  red[2][tid] = ssq;
  __syncthreads();
  if (tid < 64) {
    const float a0 = red[0][tid] + red[0][tid + 64] + red[0][tid + 128] + red[0][tid + 192];
    const float a1 = red[1][tid] + red[1][tid + 64] + red[1][tid + 128] + red[1][tid + 192];
    const float a2 = red[2][tid] + red[2][tid + 64] + red[2][tid + 128] + red[2][tid + 192];
    const int g = b * C_ + tid;
    unsafeAtomicAdd(&acc[g], a0);
    unsafeAtomicAdd(&acc[1024 + g], a1);
    unsafeAtomicAdd(&acc[2048 + g], a2);
  }
}

// ---------------- Pass B: parity-split lane-pair FFT + write ----------------
__global__ void __launch_bounds__(256)
fe_write_kernel(const float* __restrict__ pad, const float* __restrict__ acc,
                float* __restrict__ out) {
  const int tid = threadIdx.x;
  const int lam = (tid >> 5) & 1;                       // lane-pair role (bit5)
  const int c = (tid & 31) | (((tid >> 6) & 1) << 5);   // channel 0..63
  const int b = __builtin_amdgcn_readfirstlane(blockIdx.x >> 8);
  const int l = __builtin_amdgcn_readfirstlane(((blockIdx.x & 255) << 1) | (tid >> 7));

  // fused finalize: true-scale sums -> constants matching the 2x bins
  const int g = b * C_ + c;
  const float invN = 1.0f / (float)NLF;
  const float sr = acc[g] * invN;
  const float si = acc[1024 + g] * invN;
  const float qq = acc[2048 + g] * invN;
  const float var = qq - sr * sr - si * si;
  const float mr = 2.0f * sr;
  const float mi = 2.0f * si;
  const float is = 0.5f * rsqrtf(var);

  // lam-adjusted base: lam0 reads samples 4j,4j+1; lam1 reads 4j+2,4j+3
  const float* base = pad + ((size_t)(b * LP + l)) * C_ + c + (lam << 7);

  // ---- load 32 complex (bit-reversed), window applied ----
  float zx[32], zy[32];
#pragma unroll
  for (int j = 0; j < 32; ++j) {
    const int s0 = 4 * bitrev5(j);
    const float wA = lam ? TBL.win[s0 + 2] : TBL.win[s0];
    const float wB = lam ? TBL.win[s0 + 3] : TBL.win[s0 + 1];
    zx[j] = wA * base[s0 * C_];
    zy[j] = wB * base[s0 * C_ + C_];
  }

  // ---- 32-pt complex DIT FFT (fully unrolled, literal twiddles) ----
#pragma unroll
  for (int s = 0; s < 5; ++s) {
    const int half = 1 << s;
    const int len = half << 1;
#pragma unroll
    for (int j = 0; j < half; ++j) {
      const float wr = TBL.t32r[j << (4 - s)];
      const float wi = TBL.t32i[j << (4 - s)];
#pragma unroll
      for (int base2 = 0; base2 < 32; base2 += len) {
        const int a = base2 + j;
        const int b2 = a + half;
        const float tr = wr * zx[b2] - wi * zy[b2];
        const float ti = wr * zy[b2] + wi * zx[b2];
        zx[b2] = zx[a] - tr;
        zy[b2] = zy[a] - ti;
        zx[a] += tr;
        zy[a] += ti;
      }
    }
  }
  // lam0: z = E[0..31], lam1: z = O[0..31]

  // ---- exchange + canonicalize: m[] = kept own, r[] = received partner ----
  // lam0: m[j]=E[2j],   r[j]=O[2j]   (sends E[2j+1], keeps E[2j])
  // lam1: m[j]=O[2j+1], r[j]=E[2j+1] (sends O[2j],   keeps O[2j+1])
  float mx[16], my[16], rx[16], ry[16];
#pragma unroll
  for (int j = 0; j < 16; ++j) {
    const float sx = lam ? zx[2 * j] : zx[2 * j + 1];
    const float sy = lam ? zy[2 * j] : zy[2 * j + 1];
    mx[j] = lam ? zx[2 * j + 1] : zx[2 * j];
    my[j] = lam ? zy[2 * j + 1] : zy[2 * j];
    rx[j] = __shfl_xor(sx, 32, 64);
    ry[j] = __shfl_xor(sy, 32, 64);
  }

  float* obase = out + (((size_t)(b * L_ + l)) * F_) * C_ + c;
  float* const pK = obase + lam * C_;           // bin k    = 2t+lam
  float* const p64 = obase + (64 - lam) * C_;   // bin 64-k
  float* const p3m = obase + (32 - lam) * C_;   // bin 32-k
  float* const p3p = obase + (32 + lam) * C_;   // bin 32+k

  auto emitp = [&](float* p, int off, float Xr, float Xi) {
    const float dr = Xr - mr;
    const float di = Xi - mi;
    const float amp = fast_sqrt(__builtin_fmaf(dr, dr, di * di)) * is;
    __builtin_nontemporal_store(amp, p + off);
  };

  // ---- unified bin loop: k = 2t+lam, m = 32-k. Each iteration builds
  //      Z[k], Z[32+k], Z[m], Z[64-k] and emits bins {k, 64-k, 32-k, 32+k}.
  //      t=0 lam0 covers bins 0/64/32; self/dup iterations write identical
  //      values twice (deterministic, benign). ----
#pragma unroll
  for (int t = 0; t <= 8; ++t) {
    const int i16 = (16 - t) & 15;
    const float Ekx = lam ? rx[t] : mx[t];
    const float Eky = lam ? ry[t] : my[t];
    const float Okx = lam ? mx[t] : rx[t];
    const float Oky = lam ? my[t] : ry[t];
    const float Emx = lam ? rx[15 - t] : mx[i16];
    const float Emy = lam ? ry[15 - t] : my[i16];
    const float Omx = lam ? mx[15 - t] : rx[i16];
    const float Omy = lam ? my[15 - t] : ry[i16];
    const float twkr = lam ? TBL.e64r[2 * t + 1] : TBL.e64r[2 * t];
    const float twki = lam ? TBL.e64i[2 * t + 1] : TBL.e64i[2 * t];
    const float twmr = lam ? TBL.e64r[31 - 2 * t] : TBL.e64r[32 - 2 * t];
    const float twmi = lam ? TBL.e64i[31 - 2 * t] : TBL.e64i[32 - 2 * t];
    const float ckr = lam ? TBL.c128r[2 * t + 1] : TBL.c128r[2 * t];
    const float cki = lam ? TBL.c128i[2 * t + 1] : TBL.c128i[2 * t];
    const float cmr = lam ? TBL.c128r[31 - 2 * t] : TBL.c128r[32 - 2 * t];
    const float cmi = lam ? TBL.c128i[31 - 2 * t] : TBL.c128i[32 - 2 * t];

    // a = W64^k * O[k]; Z[k] = E[k]+a, Z[32+k] = E[k]-a
    const float akx = twkr * Okx - twki * Oky;
    const float aky = twkr * Oky + twki * Okx;
    const float Zkx = Ekx + akx, Zky = Eky + aky;  // Z[k]
    const float Zpx = Ekx - akx, Zpy = Eky - aky;  // Z[32+k]
    const float bmx = twmr * Omx - twmi * Omy;
    const float bmy = twmr * Omy + twmi * Omx;
    const float Zmx = Emx + bmx, Zmy = Emy + bmy;  // Z[32-k]
    const float Znx = Emx - bmx, Zny = Emy - bmy;  // Z[64-k]

    // pair (k, 64-k): uses Z[k], Z[64-k]
    {
      const float Er = Zkx + Znx, Ei = Zky - Zny;
      const float Or2 = Zky + Zny, Oi2 = Znx - Zkx;
      const float wOr = ckr * Or2 - cki * Oi2;
      const float wOi = ckr * Oi2 + cki * Or2;
      emitp(pK, 2 * t * C_, Er + wOr, Ei + wOi);
      emitp(p64, -2 * t * C_, Er - wOr, wOi - Ei);
    }
    // pair (32-k, 32+k): uses Z[32-k], Z[32+k]
    {
      const float Er = Zmx + Zpx, Ei = Zmy - Zpy;
      const float Or2 = Zmy + Zpy, Oi2 = Zpx - Zmx;
      const float wOr = cmr * Or2 - cmi * Oi2;
      const float wOi = cmr * Oi2 + cmi * Or2;
      emitp(p3m, -2 * t * C_, Er + wOr, Ei + wOi);
      emitp(p3p, 2 * t * C_, Er - wOr, wOi - Ei);
    }
  }
}

extern "C" void kernel_launch(void* const* d_in, const int* in_sizes, int n_in,
                              void* d_out, int out_size, void* d_ws, size_t ws_size,
                              hipStream_t stream) {
  const float* seq = (const float*)d_in[0];
  float* out = (float*)d_out;
  float* ws = (float*)d_ws;
  float* acc = ws;          // 3072 floats
  float* pad = ws + 4096;   // 16*640*64 = 655360 floats (2.62 MB)

  hipMemsetAsync(acc, 0, 3072 * sizeof(float), stream);

  fe_pad_kernel<<<(B_ * LP * C_) / 256, 256, 0, stream>>>(seq, pad);
  fe_reduce_kernel<<<(B_ * L_) / 4, 256, 0, stream>>>(pad, acc);
  // 2 frames per block, lane pairs (i, i^32) share one (b,l,c) frame
  fe_write_kernel<<<B_ * L_ / 2, 256, 0, stream>>>(pad, acc, out);
}